// Round 8
// baseline (197.374 us; speedup 1.0000x reference)
//
#include <hip/hip_runtime.h>
#include <stdint.h>

#define NHEAD  16
#define SEQ    2048
#define DMODEL 1024
#define BATCH  4

typedef __attribute__((ext_vector_type(4))) float f32x4;
typedef __attribute__((ext_vector_type(8))) __bf16 bf16x8;
typedef __attribute__((ext_vector_type(8))) unsigned short u16x8;

__device__ __forceinline__ unsigned short f2bf(float f) {
    unsigned int u = __builtin_bit_cast(unsigned int, f);
    u += 0x7FFFu + ((u >> 16) & 1u);   // RNE
    return (unsigned short)(u >> 16);
}

__device__ __forceinline__ unsigned int cvt_pk_bf16(float lo, float hi) {
    unsigned int r;
    asm("v_cvt_pk_bf16_f32 %0, %1, %2" : "=v"(r) : "v"(lo), "v"(hi));
    return r;
}

// async global->LDS, 16B per lane. LDS dest must be wave-uniform base + lane*16.
__device__ __forceinline__ void gload_lds16(const void* g, void* l) {
    __builtin_amdgcn_global_load_lds(
        (const __attribute__((address_space(1))) unsigned int*)(uintptr_t)g,
        (__attribute__((address_space(3))) unsigned int*)(uintptr_t)l,
        16, 0, 0);
}

__device__ __forceinline__ bf16x8 lds_frag(const unsigned short* p) {
    return __builtin_bit_cast(bf16x8, *(const u16x8*)p);
}

__device__ __forceinline__ bf16x8 gfrag(const unsigned short* p) {
    return __builtin_bit_cast(bf16x8, *(const u16x8*)p);
}

// ---------------- fp32 -> bf16 conversion ----------------
__global__ __launch_bounds__(256) void cvt_f32_bf16(const float* __restrict__ src,
                                                    unsigned short* __restrict__ dst, int n4) {
    int i = blockIdx.x * 256 + threadIdx.x;
    if (i < n4) {
        float4 v = ((const float4*)src)[i];
        ushort4 o;
        o.x = f2bf(v.x); o.y = f2bf(v.y); o.z = f2bf(v.z); o.w = f2bf(v.w);
        ((ushort4*)dst)[i] = o;
    }
}

__global__ __launch_bounds__(256) void cvt_weights(const float* __restrict__ w0,
                                                   const float* __restrict__ w1,
                                                   const float* __restrict__ w2,
                                                   const float* __restrict__ w3,
                                                   unsigned short* __restrict__ dst) {
    int which = blockIdx.x >> 10;
    int i = (blockIdx.x & 1023) * 256 + threadIdx.x;
    const float* src = which == 0 ? w0 : which == 1 ? w1 : which == 2 ? w2 : w3;
    unsigned short* d = dst + (size_t)which * 1024 * 1024;
    float4 v = ((const float4*)src)[i];
    ushort4 o;
    o.x = f2bf(v.x); o.y = f2bf(v.y); o.z = f2bf(v.z); o.w = f2bf(v.w);
    ((ushort4*)d)[i] = o;
}

// ---------------- 8-phase-style GEMM: C = A(Mx1024) * W(Nx1024)^T ----------------
// BM=256, BN=128, BK=64. 512 threads = 8 waves (4 wm x 2 wn); per-wave C = 64x64.
// 3-buffer LDS ring (144 KB dynamic): compute kt from buf[kt%3], stage kt+2 into buf[(kt+2)%3].
// Counted vmcnt(6) at K-tile boundary (kt+1's 6 loads stay in flight); single barrier per K-tile.
// LDS chunk-XOR swizzle: 16B chunk c of row r stored at c^(r&7) (pre-swizzled global source).
// MODE 0: QKV epilogue (RoPE for Q/K, transpose for V; Q pre-scaled by 1/8*log2e)
// MODE 1: fp32 output (d_out)
template <int MODE>
__global__ __launch_bounds__(512, 1) void gemm256(const unsigned short* __restrict__ A,
                                                  const unsigned short* __restrict__ Wc,
                                                  unsigned short* __restrict__ qw,
                                                  unsigned short* __restrict__ kw,
                                                  unsigned short* __restrict__ vw,
                                                  float* __restrict__ fout) {
    extern __shared__ __align__(16) unsigned short lds[];
    unsigned short* As = lds;              // [3][256*64]
    unsigned short* Bs = lds + 3 * 16384;  // [3][128*64]

    const int tid  = threadIdx.x;
    const int lane = tid & 63;
    const int wid  = tid >> 6;
    const int wm = wid >> 1, wn = wid & 1;
    const int l15 = lane & 15, lg = lane >> 4;
    const int l7 = l15 & 7;

    const int tn = blockIdx.x;
    const int m0 = blockIdx.y * 256, n0 = tn * 128;

    // staging: per K-tile, A = 4 passes, B = 2 passes of 16B/thread (6 loads total)
    auto STAGE_A = [&](int kt, int buf, int is) {
        int e = (is * 512 + tid) * 8;             // elem in 256x64 tile
        int row = e >> 6, c = (e >> 3) & 7;
        gload_lds16(A + (size_t)(m0 + row) * 1024 + kt * 64 + ((c ^ (row & 7)) << 3),
                    &As[buf * 16384 + e]);
    };
    auto STAGE_B = [&](int kt, int buf, int is) {
        int e = (is * 512 + tid) * 8;             // elem in 128x64 tile
        int row = e >> 6, c = (e >> 3) & 7;
        gload_lds16(Wc + (size_t)(n0 + row) * 1024 + kt * 64 + ((c ^ (row & 7)) << 3),
                    &Bs[buf * 8192 + e]);
    };

    // prologue: stage kt0 (6 loads, oldest) then kt1 (6 loads)
#pragma unroll
    for (int is = 0; is < 4; ++is) STAGE_A(0, 0, is);
#pragma unroll
    for (int is = 0; is < 2; ++is) STAGE_B(0, 0, is);
#pragma unroll
    for (int is = 0; is < 4; ++is) STAGE_A(1, 1, is);
#pragma unroll
    for (int is = 0; is < 2; ++is) STAGE_B(1, 1, is);

    f32x4 acc[4][4];
#pragma unroll
    for (int i = 0; i < 4; i++)
#pragma unroll
        for (int j = 0; j < 4; j++) acc[i][j] = f32x4{0.f, 0.f, 0.f, 0.f};

    const int aoff = (wm * 64 + l15) * 64;   // + i*16*64
    const int boff = (wn * 64 + l15) * 64;   // + n*16*64
    const int c0 = (lg ^ l7) << 3;           // ks=0 swizzled chunk
    const int c1 = ((4 + lg) ^ l7) << 3;     // ks=1 swizzled chunk

    for (int kt = 0; kt < 16; ++kt) {
        const int buf  = kt % 3;
        const int buf2 = (kt + 2) % 3;
        const unsigned short* Ab = As + buf * 16384;
        const unsigned short* Bb = Bs + buf * 8192;

        // K-tile boundary: own 6 loads for kt proven landed (all but the 6 newest = kt+1's),
        // then barrier so every wave's stages are landed before any wave reads.
        if (kt < 15) asm volatile("s_waitcnt vmcnt(6)" ::: "memory");
        else         asm volatile("s_waitcnt vmcnt(0)" ::: "memory");
        __builtin_amdgcn_sched_barrier(0);
        __builtin_amdgcn_s_barrier();

        // ---- phase 0 (ks=0): stage 3, read 8, 16 MFMA ----
        if (kt + 2 < 16) {
            STAGE_A(kt + 2, buf2, 0);
            STAGE_A(kt + 2, buf2, 1);
            STAGE_A(kt + 2, buf2, 2);
        }
        {
            bf16x8 a[4], b[4];
#pragma unroll
            for (int i = 0; i < 4; i++) a[i] = lds_frag(Ab + aoff + i * 1024 + c0);
#pragma unroll
            for (int n = 0; n < 4; n++) b[n] = lds_frag(Bb + boff + n * 1024 + c0);
            asm volatile("s_waitcnt lgkmcnt(0)" ::: "memory");
            __builtin_amdgcn_sched_barrier(0);
            __builtin_amdgcn_s_setprio(1);
#pragma unroll
            for (int i = 0; i < 4; i++)
#pragma unroll
                for (int n = 0; n < 4; n++)
                    acc[i][n] = __builtin_amdgcn_mfma_f32_16x16x32_bf16(a[i], b[n], acc[i][n], 0, 0, 0);
            __builtin_amdgcn_s_setprio(0);
        }

        // ---- phase 1 (ks=1): stage 3, read 8, 16 MFMA ----
        if (kt + 2 < 16) {
            STAGE_A(kt + 2, buf2, 3);
            STAGE_B(kt + 2, buf2, 0);
            STAGE_B(kt + 2, buf2, 1);
        }
        {
            bf16x8 a[4], b[4];
#pragma unroll
            for (int i = 0; i < 4; i++) a[i] = lds_frag(Ab + aoff + i * 1024 + c1);
#pragma unroll
            for (int n = 0; n < 4; n++) b[n] = lds_frag(Bb + boff + n * 1024 + c1);
            asm volatile("s_waitcnt lgkmcnt(0)" ::: "memory");
            __builtin_amdgcn_sched_barrier(0);
            __builtin_amdgcn_s_setprio(1);
#pragma unroll
            for (int i = 0; i < 4; i++)
#pragma unroll
                for (int n = 0; n < 4; n++)
                    acc[i][n] = __builtin_amdgcn_mfma_f32_16x16x32_bf16(a[i], b[n], acc[i][n], 0, 0, 0);
            __builtin_amdgcn_s_setprio(0);
        }
    }

    // epilogue: C[m][n], m = m0+wm*64+i*16+lg*4+r, n = n0+wn*64+j*16+l15
    if (MODE == 1) {
        float* out = fout;
#pragma unroll
        for (int i = 0; i < 4; i++)
#pragma unroll
            for (int r = 0; r < 4; r++) {
                int m = m0 + wm * 64 + i * 16 + lg * 4 + r;
                float* orow = out + (size_t)m * 1024 + n0 + wn * 64 + l15;
#pragma unroll
                for (int j = 0; j < 4; j++) orow[j * 16] = acc[i][j][r];
            }
    } else if (tn >= 16) {   // V -> (b,h,dk,s) transposed
        unsigned short* out = vw;
#pragma unroll
        for (int i = 0; i < 4; i++)
#pragma unroll
            for (int r = 0; r < 4; r++) {
                int m = m0 + wm * 64 + i * 16 + lg * 4 + r;
                int b = m >> 11, s = m & 2047;
#pragma unroll
                for (int j = 0; j < 4; j++) {
                    int n = n0 + wn * 64 + j * 16 + l15;
                    int h = (n >> 6) & 15, dk = n & 63;
                    out[((size_t)(b * NHEAD + h) * 64 + dk) * SEQ + s] = f2bf(acc[i][j][r]);
                }
            }
    } else {                 // Q or K with RoPE -> (b,h,s,dk)
        unsigned short* out = (tn < 8) ? qw : kw;
        const float qscale = (tn < 8) ? 0.18033688011112042f : 1.0f;   // 1/8*log2(e) for Q
        const float L2T = 13.287712379549449f;   // log2(10000)
        float invf[4];
#pragma unroll
        for (int j = 0; j < 4; j++) {
            int idx = j * 16 + l15;          // n % 64
            int t = idx >> 1;
            invf[j] = exp2f(-((float)(2 * t) * (1.0f / 64.0f)) * L2T);
        }
        const int par = l15 & 1;
#pragma unroll
        for (int i = 0; i < 4; i++)
#pragma unroll
            for (int r = 0; r < 4; r++) {
                int m = m0 + wm * 64 + i * 16 + lg * 4 + r;
                int b = m >> 11, s = m & 2047;
                float fs = (float)s;
#pragma unroll
                for (int j = 0; j < 4; j++) {
                    float v = acc[i][j][r];
                    float other = __shfl_xor(v, 1);
                    float sn, cs;
                    __sincosf(fs * invf[j], &sn, &cs);
                    float y = par ? fmaf(v, cs, other * sn) : fmaf(v, cs, -other * sn);
                    y *= qscale;
                    int n = n0 + wn * 64 + j * 16 + l15;
                    int h = (n >> 6) & 15, dk = n & 63;
                    out[((size_t)(b * NHEAD + h) * SEQ + s) * 64 + dk] = f2bf(y);
                }
            }
    }
}

// ---------------- causal flash attention: balanced pairing (tile p + tile 31-p) ----------------
// Q,K in (bh, s, dk) (Q pre-scaled by 1/8*log2e); V in (bh, dk, s). Out (b,s,dmodel) bf16.
__global__ __launch_bounds__(256, 4) void flash_attn(const unsigned short* __restrict__ Qw,
                                                     const unsigned short* __restrict__ Kw,
                                                     const unsigned short* __restrict__ Vw,
                                                     unsigned short* __restrict__ Ow) {
    __shared__ __align__(16) unsigned short Ks[2][64 * 64];
    __shared__ __align__(16) unsigned short Vs[2][64 * 64];   // [dk][kv]
    __shared__ __align__(16) unsigned short Ps[64 * 64];      // [q][kv], swizzled, reused A/B

    const int tid  = threadIdx.x;
    const int lane = tid & 63;
    const int w    = tid >> 6;
    const int l15 = lane & 15, lg = lane >> 4;
    const int l7 = l15 & 7;

    const int logical = (blockIdx.x & 7) * 128 + (blockIdx.x >> 3);
    const int bh = logical >> 4;
    const int p  = logical & 15;       // pair index: q-tiles p and 31-p
    const int qbB = 31 - p;
    const int ktmax = qbB;

    const unsigned short* Kbh = Kw + (size_t)bh * (SEQ * 64);
    const unsigned short* Vbh = Vw + (size_t)bh * (64 * SEQ);

    const int qrow0 = w * 16;
    const int prow  = qrow0 + l15;

    const unsigned short* QrowA = Qw + (size_t)bh * (SEQ * 64) + (size_t)(p * 64 + prow) * 64;
    const unsigned short* QrowB = Qw + (size_t)bh * (SEQ * 64) + (size_t)(qbB * 64 + prow) * 64;
    bf16x8 qA0 = gfrag(QrowA + lg * 8), qA1 = gfrag(QrowA + 32 + lg * 8);
    bf16x8 qB0 = gfrag(QrowB + lg * 8), qB1 = gfrag(QrowB + 32 + lg * 8);

    auto STAGE = [&](int kt2, int bufi) {
#pragma unroll
        for (int is = 0; is < 2; ++is) {
            int e = (is * 256 + tid) * 8;
            int row = e >> 6, c = (e >> 3) & 7;
            int sc = (c ^ (row & 7)) << 3;
            gload_lds16(Kbh + (size_t)kt2 * 4096 + row * 64 + sc, &Ks[bufi][e]);
            gload_lds16(Vbh + (size_t)row * SEQ + kt2 * 64 + sc, &Vs[bufi][e]);
        }
    };

    STAGE(0, 0);

    f32x4 oaccA[4], oaccB[4];
#pragma unroll
    for (int f = 0; f < 4; f++) { oaccA[f] = f32x4{0.f, 0.f, 0.f, 0.f}; oaccB[f] = f32x4{0.f, 0.f, 0.f, 0.f}; }
    float mA = -3.0e38f, lA = 0.f, mB = -3.0e38f, lB = 0.f;

    unsigned short* pbase = &Ps[prow * 64];
    const unsigned short* prd = &Ps[prow * 64];

    __syncthreads();

    for (int kt = 0; kt <= ktmax; ++kt) {
        const int cur = kt & 1;
        if (kt < ktmax) STAGE(kt + 1, cur ^ 1);

        auto PROC = [&](bf16x8 q0, bf16x8 q1, f32x4* oacc, float& mrun, float& lrun, bool diag) {
            f32x4 st[4];
#pragma unroll
            for (int f = 0; f < 4; f++) st[f] = f32x4{0.f, 0.f, 0.f, 0.f};
            __builtin_amdgcn_s_setprio(1);
#pragma unroll
            for (int ks = 0; ks < 2; ++ks) {
                bf16x8 qk = (ks == 0) ? q0 : q1;
#pragma unroll
                for (int f = 0; f < 4; f++) {
                    bf16x8 kfrag = lds_frag(&Ks[cur][(f * 16 + l15) * 64 + (((ks * 4 + lg) ^ l7) << 3)]);
                    st[f] = __builtin_amdgcn_mfma_f32_16x16x32_bf16(kfrag, qk, st[f], 0, 0, 0);
                }
            }
            __builtin_amdgcn_s_setprio(0);

            if (diag) {
#pragma unroll
                for (int f = 0; f < 4; f++)
#pragma unroll
                    for (int r = 0; r < 4; r++) {
                        int kv = f * 16 + 4 * lg + r;
                        if (kv > prow) st[f][r] = -3.0e38f;
                    }
            }

            float pm = fmaxf(fmaxf(fmaxf(st[0][0], st[0][1]), fmaxf(st[0][2], st[0][3])),
                             fmaxf(fmaxf(st[1][0], st[1][1]), fmaxf(st[1][2], st[1][3])));
            pm = fmaxf(pm, fmaxf(fmaxf(fmaxf(st[2][0], st[2][1]), fmaxf(st[2][2], st[2][3])),
                                 fmaxf(fmaxf(st[3][0], st[3][1]), fmaxf(st[3][2], st[3][3]))));
            pm = fmaxf(pm, __shfl_xor(pm, 16));
            pm = fmaxf(pm, __shfl_xor(pm, 32));

            if (!__all(pm - mrun <= 8.0f)) {
                float mnew = fmaxf(mrun, pm);
                float sc0 = exp2f(mrun - mnew);
                mrun = mnew;
                lrun *= sc0;
#pragma unroll
                for (int r = 0; r < 4; r++) {
                    float so = __shfl(sc0, lg * 4 + r);
#pragma unroll
                    for (int f = 0; f < 4; f++) oacc[f][r] *= so;
                }
            }

            float lsum = 0.f;
#pragma unroll
            for (int f = 0; f < 4; f++)
#pragma unroll
                for (int r = 0; r < 4; r++) {
                    float e = exp2f(st[f][r] - mrun);
                    st[f][r] = e;
                    lsum += e;
                }
            lsum += __shfl_xor(lsum, 16);
            lsum += __shfl_xor(lsum, 32);
            lrun += lsum;

            {
                const int halfoff = (lg & 1) << 2;
                const int cbase = lg >> 1;
#pragma unroll
                for (int f = 0; f < 4; f++) {
                    uint2 pw;
                    pw.x = cvt_pk_bf16(st[f][0], st[f][1]);
                    pw.y = cvt_pk_bf16(st[f][2], st[f][3]);
                    *(uint2*)(pbase + (((2 * f + cbase) ^ l7) << 3) + halfoff) = pw;
                }
            }

            __builtin_amdgcn_s_setprio(1);
#pragma unroll
            for (int ks = 0; ks < 2; ++ks) {
                bf16x8 pa = lds_frag(prd + (((ks * 4 + lg) ^ l7) << 3));
#pragma unroll
                for (int f = 0; f < 4; f++) {
                    bf16x8 vb = lds_frag(&Vs[cur][(f * 16 + l15) * 64 + (((ks * 4 + lg) ^ l7) << 3)]);
                    oacc[f] = __builtin_amdgcn_mfma_f32_16x16x32_bf16(pa, vb, oacc[f], 0, 0, 0);
                }
            }
            __builtin_amdgcn_s_setprio(0);
        };

        if (kt <= p) PROC(qA0, qA1, oaccA, mA, lA, kt == p);
        PROC(qB0, qB1, oaccB, mB, lB, kt == ktmax);

        __syncthreads();
    }

    const int b = bh >> 4, h = bh & 15;
#pragma unroll
    for (int r = 0; r < 4; r++) {
        float lrA = __shfl(lA, lg * 4 + r);
        float invA = 1.0f / lrA;
        int sgA = p * 64 + qrow0 + lg * 4 + r;
        unsigned short* orowA = Ow + ((size_t)(b * SEQ + sgA) * DMODEL) + h * 64 + l15;
#pragma unroll
        for (int f = 0; f < 4; f++) orowA[f * 16] = f2bf(oaccA[f][r] * invA);

        float lrB = __shfl(lB, lg * 4 + r);
        float invB = 1.0f / lrB;
        int sgB = qbB * 64 + qrow0 + lg * 4 + r;
        unsigned short* orowB = Ow + ((size_t)(b * SEQ + sgB) * DMODEL) + h * 64 + l15;
#pragma unroll
        for (int f = 0; f < 4; f++) orowB[f * 16] = f2bf(oaccB[f][r] * invB);
    }
}

extern "C" void kernel_launch(void* const* d_in, const int* in_sizes, int n_in,
                              void* d_out, int out_size, void* d_ws, size_t ws_size,
                              hipStream_t stream) {
    const float* x  = (const float*)d_in[0];
    const float* wq = (const float*)d_in[1];
    const float* wk = (const float*)d_in[2];
    const float* wv = (const float*)d_in[3];
    const float* wo = (const float*)d_in[4];

    unsigned short* ws = (unsigned short*)d_ws;
    const size_t MEL = (size_t)8192 * 1024;   // 8M elements
    const size_t WEL = (size_t)1024 * 1024;   // 1M elements
    unsigned short* xb  = ws;
    unsigned short* wqb = xb + MEL;           // 4 weights contiguous: wq|wk|wv|wo
    unsigned short* wob = wqb + 3 * WEL;
    unsigned short* qw  = wob + WEL;
    unsigned short* kw  = qw + MEL;
    unsigned short* vw  = kw + MEL;
    unsigned short* ow  = vw + MEL;

    const int GEMM_LDS = (3 * 16384 + 3 * 8192) * 2;   // 147456 B
    (void)hipFuncSetAttribute((const void*)gemm256<0>,
                              hipFuncAttributeMaxDynamicSharedMemorySize, GEMM_LDS);
    (void)hipFuncSetAttribute((const void*)gemm256<1>,
                              hipFuncAttributeMaxDynamicSharedMemorySize, GEMM_LDS);

    cvt_f32_bf16<<<8192, 256, 0, stream>>>(x, xb, (int)(MEL / 4));
    cvt_weights<<<4096, 256, 0, stream>>>(wq, wk, wv, wo, wqb);

    gemm256<0><<<dim3(24, 32), 512, GEMM_LDS, stream>>>(xb, wqb, qw, kw, vw, nullptr);

    flash_attn<<<1024, 256, 0, stream>>>(qw, kw, vw, ow);

    gemm256<1><<<dim3(8, 32), 512, GEMM_LDS, stream>>>(ow, wob, nullptr, nullptr, nullptr, (float*)d_out);
}